// Round 1
// baseline (632.623 us; speedup 1.0000x reference)
//
#include <hip/hip_runtime.h>

// RESCAL bilinear scoring: pos = h^T R t, neg = nh^T R nt, R shared per relation.
// Strategy: bucket triples by relation (200 buckets), then one LDS-resident R per
// block amortized over the bucket's triples. fp32 vector-ALU bound (~7 us floor).

#define NB    16384   // batch of triples
#define D     128     // embedding dim
#define NREL  200     // distinct relations
#define SPLIT 4       // blocks per relation
#define NT    4       // triples per wave-group
#define TV    (2*NT)  // t-vectors (t + nt) per wave-group

// ---------------- bucketing: counting sort by relation ----------------
__global__ __launch_bounds__(1024) void rescal_bucket(
    const int* __restrict__ rel, int* __restrict__ order, int* __restrict__ start)
{
    __shared__ int cnt[NREL];
    __shared__ int cur[NREL];
    const int tid = threadIdx.x;
    for (int i = tid; i < NREL; i += 1024) cnt[i] = 0;
    __syncthreads();
    for (int i = tid; i < NB; i += 1024) atomicAdd(&cnt[rel[i]], 1);
    __syncthreads();
    // parallel exclusive scan: thread t sums cnt[k] for k < t (independent
    // broadcast LDS reads -> pipelined, no serial dependence chain)
    if (tid <= NREL) {
        int s = 0;
        for (int k = 0; k < NREL; ++k) { int c = cnt[k]; s += (k < tid) ? c : 0; }
        start[tid] = s;
        if (tid < NREL) cur[tid] = s;
    }
    __syncthreads();
    for (int i = tid; i < NB; i += 1024) {
        int p = atomicAdd(&cur[rel[i]], 1);
        order[p] = i;
    }
}

// ---------------- scoring ----------------
// grid = NREL*SPLIT blocks of 256 threads. r = bid % NREL so the SPLIT blocks of
// one relation land on the same XCD (NREL % 8 == 0) and share R in its L2.
__global__ __launch_bounds__(256, 2) void rescal_score(
    const int* __restrict__ heads, const int* __restrict__ tails,
    const int* __restrict__ nheads, const int* __restrict__ ntails,
    const float* __restrict__ ent, const float* __restrict__ relm,
    const int* __restrict__ order, const int* __restrict__ start,
    float* __restrict__ out)
{
    // R swizzled: byte ^= ((byte>>9)&7)<<4  -> b128 row-reads spread over all banks
    __shared__ __align__(16) float Rlds[D * D];        // 64 KB
    __shared__ __align__(16) float tlds[4][TV][D];     // 16 KB (per-wave private)

    const int tid  = threadIdx.x;
    const int wave = tid >> 6;
    const int lane = tid & 63;
    const int r = blockIdx.x % NREL;
    const int j = blockIdx.x / NREL;

    // stage R -> LDS (swizzled), coalesced float4
    {
        const float4* Rg = (const float4*)(relm + (size_t)r * (D * D));
        char* Rb = (char*)Rlds;
        #pragma unroll
        for (int k = 0; k < (D * D / 4) / 256; ++k) {
            int idx = tid + k * 256;
            unsigned lin = (unsigned)idx * 16u;
            unsigned swz = lin ^ (((lin >> 9) & 7u) << 4);
            *(float4*)(Rb + swz) = Rg[idx];
        }
    }

    const int bs = start[r];
    const int n  = start[r + 1] - bs;
    __syncthreads();                       // R visible to all waves
    if (n == 0) return;
    const int per   = (n + SPLIT - 1) / SPLIT;
    const int mybeg = j * per;
    const int mycnt = min(n - mybeg, per);
    if (mycnt <= 0) return;

    const unsigned xsw   = (unsigned)(lane & 7) << 4;   // (d&7)<<4, same for d=l and l+64
    const unsigned baseA = (unsigned)lane * (D * 4);
    const unsigned baseB = (unsigned)(lane + 64) * (D * 4);
    const char* Rb = (const char*)Rlds;

    for (int s0 = wave * NT; s0 < mycnt; s0 += 4 * NT) {
        // triple ids for this group (clamp ragged tail; stores are guarded below)
        int trip[NT];
        #pragma unroll
        for (int q = 0; q < NT; ++q) {
            int s = s0 + q; if (s >= mycnt) s = mycnt - 1;
            trip[q] = order[bs + mybeg + s];
        }

        // stage t / nt rows into this wave's LDS slice (8 lanes per vector)
        {
            int v = lane >> 3;                    // 0..7
            int q = v >> 1;
            const int* idxa = (v & 1) ? ntails : tails;
            const float4* src = (const float4*)(ent + (size_t)idxa[trip[q]] * D);
            float4* dst = (float4*)(&tlds[wave][v][0]);
            int f = lane & 7;
            #pragma unroll
            for (int k = 0; k < 4; ++k) dst[f + 8 * k] = src[f + 8 * k];
        }

        // h / nh: lane l keeps rows l and l+64 in registers (coalesced loads)
        float h0[TV], h1[TV];
        #pragma unroll
        for (int v = 0; v < TV; ++v) {
            int q = v >> 1;
            const int* idxa = (v & 1) ? nheads : heads;
            const float* hrow = ent + (size_t)idxa[trip[q]] * D;
            h0[v] = hrow[lane];
            h1[v] = hrow[lane + 64];
        }

        float acc0[TV], acc1[TV];
        #pragma unroll
        for (int v = 0; v < TV; ++v) { acc0[v] = 0.f; acc1[v] = 0.f; }

        // u_v[d] = sum_e R[d,e] * t_v[e]; lane owns d = lane and lane+64.
        // per 4-col chunk: 2 swizzled R reads + 8 broadcast t reads + 64 FMAs
        #pragma unroll 4
        for (int e0 = 0; e0 < D; e0 += 4) {
            float4 ra = *(const float4*)(Rb + ((baseA + e0 * 4) ^ xsw));
            float4 rb = *(const float4*)(Rb + ((baseB + e0 * 4) ^ xsw));
            #pragma unroll
            for (int v = 0; v < TV; ++v) {
                float4 tv = *(const float4*)(&tlds[wave][v][e0]);
                acc0[v] += ra.x * tv.x + ra.y * tv.y + ra.z * tv.z + ra.w * tv.w;
                acc1[v] += rb.x * tv.x + rb.y * tv.y + rb.z * tv.z + rb.w * tv.w;
            }
        }

        // score = sum_d h[d]*u[d] : per-lane partial then 64-lane butterfly
        #pragma unroll
        for (int v = 0; v < TV; ++v) {
            float p = h0[v] * acc0[v] + h1[v] * acc1[v];
            #pragma unroll
            for (int m = 32; m >= 1; m >>= 1) p += __shfl_xor(p, m, 64);
            if (lane == 0) {
                int s = s0 + (v >> 1);
                if (s < mycnt) {
                    float* o = (v & 1) ? (out + NB) : out;
                    o[trip[v >> 1]] = p;
                }
            }
        }
    }
}

extern "C" void kernel_launch(void* const* d_in, const int* in_sizes, int n_in,
                              void* d_out, int out_size, void* d_ws, size_t ws_size,
                              hipStream_t stream)
{
    const int*   heads  = (const int*)d_in[0];
    const int*   tails  = (const int*)d_in[1];
    const int*   nheads = (const int*)d_in[2];
    const int*   ntails = (const int*)d_in[3];
    const int*   rels   = (const int*)d_in[4];
    const float* ent    = (const float*)d_in[5];
    const float* relm   = (const float*)d_in[6];
    float* out = (float*)d_out;

    // ws: order[NB] then start[NREL+1]  (~66 KB)
    int* order = (int*)d_ws;
    int* start = order + NB;

    rescal_bucket<<<1, 1024, 0, stream>>>(rels, order, start);
    rescal_score<<<NREL * SPLIT, 256, 0, stream>>>(heads, tails, nheads, ntails,
                                                   ent, relm, order, start, out);
}